// Round 4
// baseline (1110.626 us; speedup 1.0000x reference)
//
#include <hip/hip_runtime.h>
#include <stdint.h>

#define NPTS 2048
#define BATCH 4
#define KNN 20
#define EPSV 1e-5f

typedef short bf16x8 __attribute__((ext_vector_type(8)));
typedef float f32x4 __attribute__((ext_vector_type(4)));

__device__ __forceinline__ unsigned short f2bf(float f){
  union { float f; uint32_t u; } x; x.f = f;
  uint32_t u = x.u;
  uint32_t r = (u + 0x7fffu + ((u >> 16) & 1u)) >> 16;
  return (unsigned short)r;
}
__device__ __forceinline__ float bf2f(unsigned short h){
  union { uint32_t u; float f; } x; x.u = ((uint32_t)h) << 16;
  return x.f;
}

// ---------------- weight folding: bn-fold + hi/lo split ----------------
// layout: wh/wl [t][ic_half][oc(128)][ic64]
__global__ __launch_bounds__(256) void fold_wpk(const float* __restrict__ W, const float* __restrict__ g,
    const float* __restrict__ bb, const float* __restrict__ m, const float* __restrict__ vv,
    unsigned short* __restrict__ wh, unsigned short* __restrict__ wl, float* __restrict__ bias){
  int e = blockIdx.x*256 + threadIdx.x;
  if (e < 128){
    float s = g[e] / sqrtf(vv[e] + EPSV);
    bias[e] = bb[e] - m[e]*s;
  }
  if (e < 9*128*128){
    int t = e >> 14;
    int o = (e >> 7) & 127;
    int i = e & 127;
    int kh = t/3, kw = t - 3*kh;
    float s = g[o] / sqrtf(vv[o] + EPSV);
    float wv = W[((o*128 + i)*3 + kh)*3 + kw] * s;
    unsigned short h = f2bf(wv);
    unsigned short l = f2bf(wv - bf2f(h));
    int dst = ((t*2 + (i >> 6))*128 + o)*64 + (i & 63);
    wh[dst] = h; wl[dst] = l;
  }
}

__global__ __launch_bounds__(256) void fold_img(const float* __restrict__ Wimgc, const float* __restrict__ bimgc,
    const float* __restrict__ Wimg, const float* __restrict__ bimg,
    float* __restrict__ Wf, float* __restrict__ bf){
  int e = blockIdx.x*256 + threadIdx.x;
  if (e < 384){
    int j = e >> 7, c = e & 127;
    float s = 0.f;
    for (int o = 0; o < 128; ++o) s += Wimg[j*128+o] * Wimgc[o*128+c];
    Wf[e] = s;
  }
  if (e < 3){
    float s = bimg[e];
    for (int o = 0; o < 128; ++o) s += Wimg[e*128+o] * bimgc[o];
    bf[e] = s;
  }
}

// ---------------- point features (sq in fp64 to match numpy ref) ----------------
__global__ __launch_bounds__(256) void prep_x(const float* __restrict__ opc, const float* __restrict__ Win,
    const float* __restrict__ bin, float* __restrict__ x, double* __restrict__ sq){
  int p = blockIdx.x*256 + threadIdx.x;
  if (p >= BATCH*NPTS) return;
  float a = opc[p*3], b = opc[p*3+1], c = opc[p*3+2];
  double ad = a, bd = b, cd = c;
  sq[p] = (ad*ad + bd*bd) + cd*cd;
  for (int o = 0; o < 64; ++o)
    x[p*64+o] = a*Win[o*3] + b*Win[o*3+1] + c*Win[o*3+2] + bin[o];
}

__global__ __launch_bounds__(256) void prep_uv(const float* __restrict__ x, const float* __restrict__ Wg,
    float* __restrict__ u, float* __restrict__ v){
  int e = blockIdx.x*256 + threadIdx.x;
  if (e >= BATCH*NPTS*128) return;
  int p = e >> 7, o = e & 127;
  const float* xr = x + p*64;
  const float* w = Wg + o*128;
  float su = 0.f, sv = 0.f;
  for (int c = 0; c < 64; ++c){
    float xv = xr[c];
    sv += w[c]*xv;
    su += (w[64+c] - w[c])*xv;
  }
  u[e] = su; v[e] = sv;
}

// ---------------- exact top-K (smallest d2), fp64 to match numpy ref ----------------
// 2 queries per 128-thread block; d2 staged in LDS as double (32 KB).
__global__ __launch_bounds__(128) void knn_k(const float* __restrict__ pc, const double* __restrict__ sq,
    int* __restrict__ idx){
  __shared__ double dd[2][NPTS];
  int wave = threadIdx.x >> 6, lane = threadIdx.x & 63;
  int q = blockIdx.x*2 + wave;
  int b = q >> 11, n = q & 2047;
  const float* pb = pc + (size_t)b*NPTS*3;
  double qx = pb[n*3], qy = pb[n*3+1], qz = pb[n*3+2];
  double sn = sq[b*NPTS + n];
  double* d = dd[wave];
  for (int m = lane; m < NPTS; m += 64){
    double px = pb[m*3], py = pb[m*3+1], pz = pb[m*3+2];
    // products of fp32 values are exact in fp64; sum order matches numpy einsum
    double dot = (qx*px + qy*py) + qz*pz;
    d[m] = (sn + sq[b*NPTS + m]) - 2.0*dot;
  }
  __syncthreads();
  for (int it = 0; it < KNN; ++it){
    double bv = 1.0e300; int bi = -1;
    for (int m = lane; m < NPTS; m += 64){
      double val = d[m];
      if (val < bv){ bv = val; bi = m; }
    }
    for (int s = 32; s; s >>= 1){
      double ov = __shfl_xor(bv, s);
      int oi = __shfl_xor(bi, s);
      if (ov < bv || (ov == bv && oi < bi)){ bv = ov; bi = oi; }
    }
    if (lane == 0){
      d[bi] = 1.0e300;
      idx[q*KNN + it] = bi;
    }
    __syncthreads();
  }
}

// ---------------- groupnorm statistics ----------------
__global__ __launch_bounds__(256) void stats_k(const float* __restrict__ u, const float* __restrict__ v,
    const int* __restrict__ idx, float* __restrict__ sums){
  int blk = blockIdx.x;
  int b = blk >> 7;
  int n0 = (blk & 127) * 16;
  int tid = threadIdx.x;
  __shared__ int sidx[16*KNN];
  for (int i = tid; i < 16*KNN; i += 256)
    sidx[i] = idx[(b*NPTS + n0 + i/KNN)*KNN + (i % KNN)];
  __syncthreads();
  int c = tid & 127;
  int h = tid >> 7;
  float s = 0.f, ss = 0.f;
  for (int nl = 0; nl < 16; ++nl){
    float uv = u[((b*NPTS + n0 + nl) << 7) + c];
    for (int k = h; k < KNN; k += 2){
      int m = sidx[nl*KNN + k];
      float y = v[((b*NPTS + m) << 7) + c] + uv;
      s += y; ss += y*y;
    }
  }
  for (int msk = 1; msk < 32; msk <<= 1){
    s += __shfl_xor(s, msk);
    ss += __shfl_xor(ss, msk);
  }
  if ((tid & 31) == 0){
    int g = c >> 5;
    atomicAdd(&sums[(b*4 + g)*2 + 0], s);
    atomicAdd(&sums[(b*4 + g)*2 + 1], ss);
  }
}

// ---------------- normalize + lrelu + max_k + proj ----------------
__global__ __launch_bounds__(256) void fcomp_k(const float* __restrict__ u, const float* __restrict__ v,
    const int* __restrict__ idx, const float* __restrict__ sums,
    const float* __restrict__ gng, const float* __restrict__ gnb,
    const float* __restrict__ Wp, const float* __restrict__ bp, float* __restrict__ f){
  int blk = blockIdx.x;
  int b = blk >> 7;
  int n0 = (blk & 127) * 16;
  int tid = threadIdx.x;
  __shared__ int sidx[16*KNN];
  __shared__ float fpre[16*128];
  __shared__ float smu[4], sinv[4];
  if (tid < 4){
    const float cnt = 2048.0f*20.0f*32.0f;
    float sm = sums[(b*4 + tid)*2 + 0];
    float s2 = sums[(b*4 + tid)*2 + 1];
    float mu = sm/cnt;
    float var = s2/cnt - mu*mu;
    smu[tid] = mu;
    sinv[tid] = 1.0f / sqrtf(var + EPSV);
  }
  for (int i = tid; i < 16*KNN; i += 256)
    sidx[i] = idx[(b*NPTS + n0 + i/KNN)*KNN + (i % KNN)];
  __syncthreads();
  for (int e = tid; e < 2048; e += 256){
    int nl = e >> 7, c = e & 127;
    int g = c >> 5;
    float uv = u[((b*NPTS + n0 + nl) << 7) + c];
    float mu = smu[g], inv = sinv[g], gg = gng[c], gb = gnb[c];
    float best = -3.0e38f;
    for (int k = 0; k < KNN; ++k){
      int m = sidx[nl*KNN + k];
      float y = v[((b*NPTS + m) << 7) + c] + uv;
      float z = (y - mu)*inv*gg + gb;
      z = z >= 0.f ? z : 0.2f*z;
      best = fmaxf(best, z);
    }
    fpre[e] = best;
  }
  __syncthreads();
  for (int e = tid; e < 2048; e += 256){
    int nl = e >> 7, o = e & 127;
    const float* w = Wp + o*128;
    const float* fp = fpre + nl*128;
    float acc = bp[o];
    for (int c2 = 0; c2 < 128; ++c2) acc += fp[c2]*w[c2];
    f[((b*NPTS + n0 + nl) << 7) + o] = acc;
  }
}

// ---------------- per-batch grid bounds (fp64 deciders) ----------------
__device__ __forceinline__ float blk_red(float val, float* red, int tid, bool ismin){
  for (int s = 32; s; s >>= 1){
    float o = __shfl_xor(val, s);
    val = ismin ? fminf(val, o) : fmaxf(val, o);
  }
  if ((tid & 63) == 0) red[tid >> 6] = val;
  __syncthreads();
  float r = ismin ? fminf(fminf(red[0],red[1]), fminf(red[2],red[3]))
                  : fmaxf(fmaxf(red[0],red[1]), fmaxf(red[2],red[3]));
  __syncthreads();
  return r;
}

__global__ __launch_bounds__(256) void bounds_k(const float* __restrict__ pc, double* __restrict__ bnd){
  __shared__ float red[4];
  int b = blockIdx.x;
  int tid = threadIdx.x;
  const float* p = pc + (size_t)b*NPTS*3;
  // pass 1: fp32 min/max (exact — inputs are fp32)
  float mn0 = 3.0e38f, mn1 = 3.0e38f, mx0 = -3.0e38f, mx1 = -3.0e38f;
  for (int n = tid; n < NPTS; n += 256){
    float a = p[n*3], c = p[n*3+1];
    mn0 = fminf(mn0, a); mx0 = fmaxf(mx0, a);
    mn1 = fminf(mn1, c); mx1 = fmaxf(mx1, c);
  }
  mn0 = blk_red(mn0, red, tid, true);
  mx0 = blk_red(mx0, red, tid, false);
  mn1 = blk_red(mn1, red, tid, true);
  mx1 = blk_red(mx1, red, tid, false);
  // gs in fp64, matching numpy: max((pmax-pmin)[:2]) / 197
  double e0 = (double)mx0 - (double)mn0;
  double e1 = (double)mx1 - (double)mn1;
  double gs = (e0 > e1 ? e0 : e1) / 197.0;
  // pass 2: fp64 floor quotients (values are small ints — exact in fp32 reduce)
  float imn0 = 3.0e38f, imx0 = -3.0e38f, imn1 = 3.0e38f, imx1 = -3.0e38f;
  for (int n = tid; n < NPTS; n += 256){
    float i0 = (float)floor(((double)p[n*3]   - (double)mn0) / gs);
    float i1 = (float)floor(((double)p[n*3+1] - (double)mn1) / gs);
    imn0 = fminf(imn0, i0); imx0 = fmaxf(imx0, i0);
    imn1 = fminf(imn1, i1); imx1 = fmaxf(imx1, i1);
  }
  imn0 = blk_red(imn0, red, tid, true);
  imx0 = blk_red(imx0, red, tid, false);
  imn1 = blk_red(imn1, red, tid, true);
  imx1 = blk_red(imx1, red, tid, false);
  if (tid == 0){
    float c0 = floorf((imx0 + 2.0f + imn0) / 2.0f);   // small ints: exact
    float c1 = floorf((imx1 + 2.0f + imn1) / 2.0f);
    bnd[b*8+0] = (double)mn0;
    bnd[b*8+1] = (double)mn1;
    bnd[b*8+2] = gs;
    bnd[b*8+3] = (double)(100.0f - c0 - 1.0f);
    bnd[b*8+4] = (double)(100.0f - c1 - 1.0f);
  }
}

// ---------------- scatter into fp32 halo buffer (B,226,226,128) ----------------
__global__ __launch_bounds__(256) void scatter_k(const float* __restrict__ pc, const double* __restrict__ bnd,
    const float* __restrict__ f, float* __restrict__ resf){
  int wave = threadIdx.x >> 6, lane = threadIdx.x & 63;
  int q = blockIdx.x*4 + wave;
  int b = q >> 11;
  const double* bd = bnd + b*8;
  double gs = bd[2];
  double px = pc[(size_t)q*3], py = pc[(size_t)q*3+1];
  int ix0 = (int)floor((px - bd[0]) / gs);
  int iy0 = (int)floor((py - bd[1]) / gs);
  int cx = ix0 + 1 + (int)bd[3];
  int cy = iy0 + 1 + (int)bd[4];
  float f0 = f[(size_t)q*128 + lane];
  float f1 = f[(size_t)q*128 + 64 + lane];
  for (int t = 0; t < 9; ++t){
    int gx = cx + t/3 - 1;
    int gy = cy + t%3 - 1;
    if ((unsigned)gx < 200u && (unsigned)gy < 200u){
      // grid(gx,gy) lives at halo (gx+13, gy+13): 12 pad + 1 halo
      float* cell = resf + (((size_t)b*226 + (gx+13))*226 + (gy+13))*128;
      atomicAdd(cell + lane, f0);
      atomicAdd(cell + 64 + lane, f1);
    }
  }
}

// ---------------- 3x3 conv, bf16x3 (emulated fp32) MFMA implicit GEMM ----------------
// in: fp32 halo (B,226,226,128). wh/wl: [t][ic_half][oc][64] bf16.
// FUSE_FINAL=0: out fp32 halo (write interior), relu.
// FUSE_FINAL=1: += res (fp32 halo), relu, then folded 1x1 (Wf,bff) + sigmoid +
//               normalize, writing (B,3,224,224) directly to d_out.
template<int FUSE_FINAL>
__global__ __launch_bounds__(256) void conv3_k(
    const float* __restrict__ in, const unsigned short* __restrict__ wh,
    const unsigned short* __restrict__ wl, const float* __restrict__ bias,
    const float* __restrict__ res, float* __restrict__ out,
    const float* __restrict__ Wf, const float* __restrict__ bff){
  __shared__ __align__(16) char inb[46080];   // 10*18 pix * (64ch hi + 64ch lo) * 2B, swizzled
  __shared__ __align__(16) char wb[16384];    // 128 oc * 64 ic * 2B, swizzled
  __shared__ float facc[8][16][3];            // fused-final pixel accumulators
  int tx = blockIdx.x, ty = blockIdx.y, b = blockIdx.z;
  int tid = threadIdx.x;
  int lane = tid & 63, wave = tid >> 6;
  int lo = lane & 15, hi = lane >> 4;
  const int y0 = ty*8, x0 = tx*16;
  const float* ibase = in + (size_t)b*226*226*128;
  f32x4 acc[8][2];
  f32x4 zero = {0.f, 0.f, 0.f, 0.f};
  #pragma unroll
  for (int i = 0; i < 8; ++i){ acc[i][0] = zero; acc[i][1] = zero; }
  int ocb = wave*32;
  for (int ih2 = 0; ih2 < 2; ++ih2){
    __syncthreads();   // previous-iter inb readers done
    for (int ch = tid; ch < 1440; ch += 256){
      int pix = ch >> 3, ci = ch & 7;
      int iy = pix/18, ix = pix - iy*18;
      const float* src = ibase + ((size_t)(y0+iy)*226 + (x0+ix))*128 + ih2*64 + ci*8;
      float4 v0 = *(const float4*)(src);
      float4 v1 = *(const float4*)(src + 4);
      float xs[8] = {v0.x, v0.y, v0.z, v0.w, v1.x, v1.y, v1.z, v1.w};
      unsigned short h8[8], l8[8];
      #pragma unroll
      for (int j = 0; j < 8; ++j){
        unsigned short h = f2bf(xs[j]);
        h8[j] = h;
        l8[j] = f2bf(xs[j] - bf2f(h));
      }
      int base = pix*256 + ci*16;
      int swz = (ix & 7) << 4;
      *(bf16x8*)(inb + ((base      ) ^ swz)) = *(bf16x8*)h8;
      *(bf16x8*)(inb + ((base + 128) ^ swz)) = *(bf16x8*)l8;
    }
    for (int t = 0; t < 9; ++t){
      int dy = t/3, dx = t - 3*dy;
      for (int pass = 0; pass < 2; ++pass){
        const unsigned short* wsrc = (pass ? wl : wh) + (size_t)(t*2 + ih2)*8192;
        __syncthreads();   // wb readers done (also covers inb-staged visibility at t=0)
        for (int ch = tid; ch < 1024; ch += 256){
          int oc = ch >> 3, ci = ch & 7;
          bf16x8 val = *(const bf16x8*)(wsrc + oc*64 + ci*8);
          *(bf16x8*)(wb + ((oc*128 + ci*16) ^ ((oc & 7) << 4))) = val;
        }
        __syncthreads();
        #pragma unroll
        for (int kk = 0; kk < 2; ++kk){
          int oc0 = ocb + lo, oc1 = ocb + 16 + lo;
          bf16x8 b0 = *(const bf16x8*)(wb + ((oc0*128 + kk*64 + hi*16) ^ ((oc0 & 7) << 4)));
          bf16x8 b1 = *(const bf16x8*)(wb + ((oc1*128 + kk*64 + hi*16) ^ ((oc1 & 7) << 4)));
          int ix = lo + dx;
          int swz = (ix & 7) << 4;
          #pragma unroll
          for (int py = 0; py < 8; ++py){
            int pbase = ((py+dy)*18 + ix)*256;
            bf16x8 ah = *(const bf16x8*)(inb + ((pbase + kk*64 + hi*16) ^ swz));
            acc[py][0] = __builtin_amdgcn_mfma_f32_16x16x32_bf16(ah, b0, acc[py][0], 0, 0, 0);
            acc[py][1] = __builtin_amdgcn_mfma_f32_16x16x32_bf16(ah, b1, acc[py][1], 0, 0, 0);
            if (pass == 0){
              bf16x8 al = *(const bf16x8*)(inb + ((pbase + 128 + kk*64 + hi*16) ^ swz));
              acc[py][0] = __builtin_amdgcn_mfma_f32_16x16x32_bf16(al, b0, acc[py][0], 0, 0, 0);
              acc[py][1] = __builtin_amdgcn_mfma_f32_16x16x32_bf16(al, b1, acc[py][1], 0, 0, 0);
            }
          }
        }
      }
    }
  }
  if (FUSE_FINAL){
    for (int e = tid; e < 384; e += 256) ((float*)facc)[e] = 0.f;
    __syncthreads();
    float wf0[2], wf1[2], wf2[2];
    #pragma unroll
    for (int j = 0; j < 2; ++j){
      int oc = ocb + j*16 + lo;
      wf0[j] = Wf[oc]; wf1[j] = Wf[128+oc]; wf2[j] = Wf[256+oc];
    }
    #pragma unroll
    for (int py = 0; py < 8; ++py){
      int gy = ty*8 + py;
      #pragma unroll
      for (int r = 0; r < 4; ++r){
        int px = hi*4 + r;
        int gx = tx*16 + px;
        float p0 = 0.f, p1 = 0.f, p2 = 0.f;
        #pragma unroll
        for (int j = 0; j < 2; ++j){
          int oc = ocb + j*16 + lo;
          float val = acc[py][j][r] + bias[oc]
                    + res[(((size_t)b*226 + gy+1)*226 + (gx+1))*128 + oc];
          val = fmaxf(val, 0.f);
          p0 += val*wf0[j]; p1 += val*wf1[j]; p2 += val*wf2[j];
        }
        #pragma unroll
        for (int s = 1; s < 16; s <<= 1){
          p0 += __shfl_xor(p0, s);
          p1 += __shfl_xor(p1, s);
          p2 += __shfl_xor(p2, s);
        }
        if (lo == 0){
          atomicAdd(&facc[py][px][0], p0);
          atomicAdd(&facc[py][px][1], p1);
          atomicAdd(&facc[py][px][2], p2);
        }
      }
    }
    __syncthreads();
    const float mean3[3] = {0.485f, 0.456f, 0.406f};
    const float istd3[3] = {1.0f/0.229f, 1.0f/0.224f, 1.0f/0.225f};
    for (int e = tid; e < 384; e += 256){
      int py = e / 48;
      int rem = e - py*48;
      int px = rem / 3;
      int ch = rem - px*3;
      float a = facc[py][px][ch] + bff[ch];
      float s = 1.0f/(1.0f + expf(-a));
      out[(((size_t)(b*3 + ch))*224 + (ty*8+py))*224 + (tx*16+px)] = (s - mean3[ch])*istd3[ch];
    }
  } else {
    #pragma unroll
    for (int py = 0; py < 8; ++py){
      int gy = ty*8 + py;
      #pragma unroll
      for (int j = 0; j < 2; ++j){
        int oc = ocb + j*16 + lo;
        float bs = bias[oc];
        #pragma unroll
        for (int r = 0; r < 4; ++r){
          int px = hi*4 + r;
          int gx = tx*16 + px;
          float val = fmaxf(acc[py][j][r] + bs, 0.f);
          out[(((size_t)b*226 + gy+1)*226 + (gx+1))*128 + oc] = val;
        }
      }
    }
  }
}

extern "C" void kernel_launch(void* const* d_in, const int* in_sizes, int n_in,
                              void* d_out, int out_size, void* d_ws, size_t ws_size,
                              hipStream_t stream){
  const float* opc   = (const float*)d_in[0];
  const float* pc    = (const float*)d_in[1];
  const float* Win   = (const float*)d_in[2];
  const float* bin   = (const float*)d_in[3];
  const float* Wg    = (const float*)d_in[4];
  const float* gng   = (const float*)d_in[5];
  const float* gnb   = (const float*)d_in[6];
  const float* Wp    = (const float*)d_in[7];
  const float* bp    = (const float*)d_in[8];
  const float* W1    = (const float*)d_in[9];
  const float* g1    = (const float*)d_in[10];
  const float* b1    = (const float*)d_in[11];
  const float* m1    = (const float*)d_in[12];
  const float* v1    = (const float*)d_in[13];
  const float* W2    = (const float*)d_in[14];
  const float* g2    = (const float*)d_in[15];
  const float* b2    = (const float*)d_in[16];
  const float* m2    = (const float*)d_in[17];
  const float* v2    = (const float*)d_in[18];
  const float* Wimgc = (const float*)d_in[19];
  const float* bimgc = (const float*)d_in[20];
  const float* Wimg  = (const float*)d_in[21];
  const float* bimg  = (const float*)d_in[22];

  char* ws = (char*)d_ws;
  size_t off = 0;
  auto alloc = [&](size_t bytes)->char*{
    char* p = ws + off;
    off += (bytes + 255) & ~(size_t)255;
    return p;
  };
  // total ws usage ~226 MB (round-3 footprint ran OK; round-2's 328 MB faulted)
  float* x      = (float*)alloc((size_t)BATCH*NPTS*64*4);
  double* sq    = (double*)alloc((size_t)BATCH*NPTS*8);
  int*   idx    = (int*)  alloc((size_t)BATCH*NPTS*KNN*4);
  float* u      = (float*)alloc((size_t)BATCH*NPTS*128*4);
  float* v      = (float*)alloc((size_t)BATCH*NPTS*128*4);
  float* f      = (float*)alloc((size_t)BATCH*NPTS*128*4);
  float* sums   = (float*)alloc(256);
  double* bnd   = (double*)alloc(256);
  float* bias1  = (float*)alloc(512);
  float* bias2  = (float*)alloc(512);
  float* Wf     = (float*)alloc(2048);
  float* bff    = (float*)alloc(256);
  unsigned short* wh1 = (unsigned short*)alloc((size_t)9*16384*2);
  unsigned short* wl1 = (unsigned short*)alloc((size_t)9*16384*2);
  unsigned short* wh2 = (unsigned short*)alloc((size_t)9*16384*2);
  unsigned short* wl2 = (unsigned short*)alloc((size_t)9*16384*2);
  float* resf = (float*)alloc((size_t)BATCH*226*226*128*4);
  float* h1f  = (float*)alloc((size_t)BATCH*226*226*128*4);
  float* out = (float*)d_out;

  hipMemsetAsync(sums, 0, 256, stream);
  hipMemsetAsync(resf, 0, (size_t)BATCH*226*226*128*4, stream);
  hipMemsetAsync(h1f,  0, (size_t)BATCH*226*226*128*4, stream);

  fold_wpk<<<576, 256, 0, stream>>>(W1, g1, b1, m1, v1, wh1, wl1, bias1);
  fold_wpk<<<576, 256, 0, stream>>>(W2, g2, b2, m2, v2, wh2, wl2, bias2);
  fold_img<<<2, 256, 0, stream>>>(Wimgc, bimgc, Wimg, bimg, Wf, bff);
  prep_x<<<32, 256, 0, stream>>>(opc, Win, bin, x, sq);
  prep_uv<<<4096, 256, 0, stream>>>(x, Wg, u, v);
  knn_k<<<4096, 128, 0, stream>>>(opc, sq, idx);
  stats_k<<<512, 256, 0, stream>>>(u, v, idx, sums);
  fcomp_k<<<512, 256, 0, stream>>>(u, v, idx, sums, gng, gnb, Wp, bp, f);
  bounds_k<<<4, 256, 0, stream>>>(pc, bnd);
  scatter_k<<<2048, 256, 0, stream>>>(pc, bnd, f, resf);
  conv3_k<0><<<dim3(14,28,4), 256, 0, stream>>>(resf, wh1, wl1, bias1, resf, h1f, Wf, bff);
  conv3_k<1><<<dim3(14,28,4), 256, 0, stream>>>(h1f, wh2, wl2, bias2, resf, out, Wf, bff);
}

// Round 6
// 883.483 us; speedup vs baseline: 1.2571x; 1.2571x over previous
//
#include <hip/hip_runtime.h>
#include <stdint.h>

#define NPTS 2048
#define BATCH 4
#define KNN 20
#define EPSV 1e-5f

typedef short bf16x8 __attribute__((ext_vector_type(8)));
typedef float f32x4 __attribute__((ext_vector_type(4)));

__device__ __forceinline__ unsigned short f2bf(float f){
  union { float f; uint32_t u; } x; x.f = f;
  uint32_t u = x.u;
  uint32_t r = (u + 0x7fffu + ((u >> 16) & 1u)) >> 16;
  return (unsigned short)r;
}
__device__ __forceinline__ float bf2f(unsigned short h){
  union { uint32_t u; float f; } x; x.u = ((uint32_t)h) << 16;
  return x.f;
}

// ---------------- weight folding: bn-fold + hi/lo split ----------------
// layout: wh/wl [t][ic_half][oc(128)][ic64]
__global__ __launch_bounds__(256) void fold_wpk(const float* __restrict__ W, const float* __restrict__ g,
    const float* __restrict__ bb, const float* __restrict__ m, const float* __restrict__ vv,
    unsigned short* __restrict__ wh, unsigned short* __restrict__ wl, float* __restrict__ bias){
  int e = blockIdx.x*256 + threadIdx.x;
  if (e < 128){
    float s = g[e] / sqrtf(vv[e] + EPSV);
    bias[e] = bb[e] - m[e]*s;
  }
  if (e < 9*128*128){
    int t = e >> 14;
    int o = (e >> 7) & 127;
    int i = e & 127;
    int kh = t/3, kw = t - 3*kh;
    float s = g[o] / sqrtf(vv[o] + EPSV);
    float wv = W[((o*128 + i)*3 + kh)*3 + kw] * s;
    unsigned short h = f2bf(wv);
    unsigned short l = f2bf(wv - bf2f(h));
    int dst = ((t*2 + (i >> 6))*128 + o)*64 + (i & 63);
    wh[dst] = h; wl[dst] = l;
  }
}

__global__ __launch_bounds__(256) void fold_img(const float* __restrict__ Wimgc, const float* __restrict__ bimgc,
    const float* __restrict__ Wimg, const float* __restrict__ bimg,
    float* __restrict__ Wf, float* __restrict__ bf){
  int e = blockIdx.x*256 + threadIdx.x;
  if (e < 384){
    int j = e >> 7, c = e & 127;
    float s = 0.f;
    for (int o = 0; o < 128; ++o) s += Wimg[j*128+o] * Wimgc[o*128+c];
    Wf[e] = s;
  }
  if (e < 3){
    float s = bimg[e];
    for (int o = 0; o < 128; ++o) s += Wimg[e*128+o] * bimgc[o];
    bf[e] = s;
  }
}

// ---------------- point features (sq in fp64 to match numpy ref) ----------------
__global__ __launch_bounds__(256) void prep_x(const float* __restrict__ opc, const float* __restrict__ Win,
    const float* __restrict__ bin, float* __restrict__ x, double* __restrict__ sq){
  int p = blockIdx.x*256 + threadIdx.x;
  if (p >= BATCH*NPTS) return;
  float a = opc[p*3], b = opc[p*3+1], c = opc[p*3+2];
  double ad = a, bd = b, cd = c;
  sq[p] = (ad*ad + bd*bd) + cd*cd;
  for (int o = 0; o < 64; ++o)
    x[p*64+o] = a*Win[o*3] + b*Win[o*3+1] + c*Win[o*3+2] + bin[o];
}

__global__ __launch_bounds__(256) void prep_uv(const float* __restrict__ x, const float* __restrict__ Wg,
    float* __restrict__ u, float* __restrict__ v){
  int e = blockIdx.x*256 + threadIdx.x;
  if (e >= BATCH*NPTS*128) return;
  int p = e >> 7, o = e & 127;
  const float* xr = x + p*64;
  const float* w = Wg + o*128;
  float su = 0.f, sv = 0.f;
  for (int c = 0; c < 64; ++c){
    float xv = xr[c];
    sv += w[c]*xv;
    su += (w[64+c] - w[c])*xv;
  }
  u[e] = su; v[e] = sv;
}

// ---------------- exact top-K (smallest d2), fp64 to match numpy ref ----------------
__global__ __launch_bounds__(128) void knn_k(const float* __restrict__ pc, const double* __restrict__ sq,
    int* __restrict__ idx){
  __shared__ double dd[2][NPTS];
  int wave = threadIdx.x >> 6, lane = threadIdx.x & 63;
  int q = blockIdx.x*2 + wave;
  int b = q >> 11, n = q & 2047;
  const float* pb = pc + (size_t)b*NPTS*3;
  double qx = pb[n*3], qy = pb[n*3+1], qz = pb[n*3+2];
  double sn = sq[b*NPTS + n];
  double* d = dd[wave];
  for (int m = lane; m < NPTS; m += 64){
    double px = pb[m*3], py = pb[m*3+1], pz = pb[m*3+2];
    double dot = (qx*px + qy*py) + qz*pz;
    d[m] = (sn + sq[b*NPTS + m]) - 2.0*dot;
  }
  __syncthreads();
  for (int it = 0; it < KNN; ++it){
    double bv = 1.0e300; int bi = -1;
    for (int m = lane; m < NPTS; m += 64){
      double val = d[m];
      if (val < bv){ bv = val; bi = m; }
    }
    for (int s = 32; s; s >>= 1){
      double ov = __shfl_xor(bv, s);
      int oi = __shfl_xor(bi, s);
      if (ov < bv || (ov == bv && oi < bi)){ bv = ov; bi = oi; }
    }
    if (lane == 0){
      d[bi] = 1.0e300;
      idx[q*KNN + it] = bi;
    }
    __syncthreads();
  }
}

// ---------------- groupnorm statistics ----------------
__global__ __launch_bounds__(256) void stats_k(const float* __restrict__ u, const float* __restrict__ v,
    const int* __restrict__ idx, float* __restrict__ sums){
  int blk = blockIdx.x;
  int b = blk >> 7;
  int n0 = (blk & 127) * 16;
  int tid = threadIdx.x;
  __shared__ int sidx[16*KNN];
  for (int i = tid; i < 16*KNN; i += 256)
    sidx[i] = idx[(b*NPTS + n0 + i/KNN)*KNN + (i % KNN)];
  __syncthreads();
  int c = tid & 127;
  int h = tid >> 7;
  float s = 0.f, ss = 0.f;
  for (int nl = 0; nl < 16; ++nl){
    float uv = u[((b*NPTS + n0 + nl) << 7) + c];
    for (int k = h; k < KNN; k += 2){
      int m = sidx[nl*KNN + k];
      float y = v[((b*NPTS + m) << 7) + c] + uv;
      s += y; ss += y*y;
    }
  }
  for (int msk = 1; msk < 32; msk <<= 1){
    s += __shfl_xor(s, msk);
    ss += __shfl_xor(ss, msk);
  }
  if ((tid & 31) == 0){
    int g = c >> 5;
    atomicAdd(&sums[(b*4 + g)*2 + 0], s);
    atomicAdd(&sums[(b*4 + g)*2 + 1], ss);
  }
}

// ---------------- normalize + lrelu + max_k + proj ----------------
__global__ __launch_bounds__(256) void fcomp_k(const float* __restrict__ u, const float* __restrict__ v,
    const int* __restrict__ idx, const float* __restrict__ sums,
    const float* __restrict__ gng, const float* __restrict__ gnb,
    const float* __restrict__ Wp, const float* __restrict__ bp, float* __restrict__ f){
  int blk = blockIdx.x;
  int b = blk >> 7;
  int n0 = (blk & 127) * 16;
  int tid = threadIdx.x;
  __shared__ int sidx[16*KNN];
  __shared__ float fpre[16*128];
  __shared__ float smu[4], sinv[4];
  if (tid < 4){
    const float cnt = 2048.0f*20.0f*32.0f;
    float sm = sums[(b*4 + tid)*2 + 0];
    float s2 = sums[(b*4 + tid)*2 + 1];
    float mu = sm/cnt;
    float var = s2/cnt - mu*mu;
    smu[tid] = mu;
    sinv[tid] = 1.0f / sqrtf(var + EPSV);
  }
  for (int i = tid; i < 16*KNN; i += 256)
    sidx[i] = idx[(b*NPTS + n0 + i/KNN)*KNN + (i % KNN)];
  __syncthreads();
  for (int e = tid; e < 2048; e += 256){
    int nl = e >> 7, c = e & 127;
    int g = c >> 5;
    float uv = u[((b*NPTS + n0 + nl) << 7) + c];
    float mu = smu[g], inv = sinv[g], gg = gng[c], gb = gnb[c];
    float best = -3.0e38f;
    for (int k = 0; k < KNN; ++k){
      int m = sidx[nl*KNN + k];
      float y = v[((b*NPTS + m) << 7) + c] + uv;
      float z = (y - mu)*inv*gg + gb;
      z = z >= 0.f ? z : 0.2f*z;
      best = fmaxf(best, z);
    }
    fpre[e] = best;
  }
  __syncthreads();
  for (int e = tid; e < 2048; e += 256){
    int nl = e >> 7, o = e & 127;
    const float* w = Wp + o*128;
    const float* fp = fpre + nl*128;
    float acc = bp[o];
    for (int c2 = 0; c2 < 128; ++c2) acc += fp[c2]*w[c2];
    f[((b*NPTS + n0 + nl) << 7) + o] = acc;
  }
}

// ---------------- per-batch grid bounds (fp64 deciders) ----------------
__device__ __forceinline__ float blk_red(float val, float* red, int tid, bool ismin){
  for (int s = 32; s; s >>= 1){
    float o = __shfl_xor(val, s);
    val = ismin ? fminf(val, o) : fmaxf(val, o);
  }
  if ((tid & 63) == 0) red[tid >> 6] = val;
  __syncthreads();
  float r = ismin ? fminf(fminf(red[0],red[1]), fminf(red[2],red[3]))
                  : fmaxf(fmaxf(red[0],red[1]), fmaxf(red[2],red[3]));
  __syncthreads();
  return r;
}

__global__ __launch_bounds__(256) void bounds_k(const float* __restrict__ pc, double* __restrict__ bnd){
  __shared__ float red[4];
  int b = blockIdx.x;
  int tid = threadIdx.x;
  const float* p = pc + (size_t)b*NPTS*3;
  float mn0 = 3.0e38f, mn1 = 3.0e38f, mx0 = -3.0e38f, mx1 = -3.0e38f;
  for (int n = tid; n < NPTS; n += 256){
    float a = p[n*3], c = p[n*3+1];
    mn0 = fminf(mn0, a); mx0 = fmaxf(mx0, a);
    mn1 = fminf(mn1, c); mx1 = fmaxf(mx1, c);
  }
  mn0 = blk_red(mn0, red, tid, true);
  mx0 = blk_red(mx0, red, tid, false);
  mn1 = blk_red(mn1, red, tid, true);
  mx1 = blk_red(mx1, red, tid, false);
  double e0 = (double)mx0 - (double)mn0;
  double e1 = (double)mx1 - (double)mn1;
  double gs = (e0 > e1 ? e0 : e1) / 197.0;
  float imn0 = 3.0e38f, imx0 = -3.0e38f, imn1 = 3.0e38f, imx1 = -3.0e38f;
  for (int n = tid; n < NPTS; n += 256){
    float i0 = (float)floor(((double)p[n*3]   - (double)mn0) / gs);
    float i1 = (float)floor(((double)p[n*3+1] - (double)mn1) / gs);
    imn0 = fminf(imn0, i0); imx0 = fmaxf(imx0, i0);
    imn1 = fminf(imn1, i1); imx1 = fmaxf(imx1, i1);
  }
  imn0 = blk_red(imn0, red, tid, true);
  imx0 = blk_red(imx0, red, tid, false);
  imn1 = blk_red(imn1, red, tid, true);
  imx1 = blk_red(imx1, red, tid, false);
  if (tid == 0){
    float c0 = floorf((imx0 + 2.0f + imn0) / 2.0f);
    float c1 = floorf((imx1 + 2.0f + imn1) / 2.0f);
    bnd[b*8+0] = (double)mn0;
    bnd[b*8+1] = (double)mn1;
    bnd[b*8+2] = gs;
    bnd[b*8+3] = (double)(100.0f - c0 - 1.0f);
    bnd[b*8+4] = (double)(100.0f - c1 - 1.0f);
  }
}

// ---------------- scatter into fp32 halo buffer (B,226,226,128) ----------------
__global__ __launch_bounds__(256) void scatter_k(const float* __restrict__ pc, const double* __restrict__ bnd,
    const float* __restrict__ f, float* __restrict__ resf){
  int wave = threadIdx.x >> 6, lane = threadIdx.x & 63;
  int q = blockIdx.x*4 + wave;
  int b = q >> 11;
  const double* bd = bnd + b*8;
  double gs = bd[2];
  double px = pc[(size_t)q*3], py = pc[(size_t)q*3+1];
  int ix0 = (int)floor((px - bd[0]) / gs);
  int iy0 = (int)floor((py - bd[1]) / gs);
  int cx = ix0 + 1 + (int)bd[3];
  int cy = iy0 + 1 + (int)bd[4];
  float f0 = f[(size_t)q*128 + lane];
  float f1 = f[(size_t)q*128 + 64 + lane];
  for (int t = 0; t < 9; ++t){
    int gx = cx + t/3 - 1;
    int gy = cy + t%3 - 1;
    if ((unsigned)gx < 200u && (unsigned)gy < 200u){
      float* cell = resf + (((size_t)b*226 + (gx+13))*226 + (gy+13))*128;
      atomicAdd(cell + lane, f0);
      atomicAdd(cell + 64 + lane, f1);
    }
  }
}

// ---------------- 3x3 conv, bf16x3 (emulated fp32) MFMA implicit GEMM ----------------
// Identical numerics/order to the round-4 PASSING kernel; the ONLY change is that
// B-fragments are read directly from global (L2-resident weights) instead of an
// LDS wb stage — removes 72 per-block barriers and the wb bank conflicts.
// in: fp32 halo (B,226,226,128). wh/wl: [t][ic_half][oc][64] bf16.
// FUSE_FINAL=0: out fp32 halo (write interior), relu.
// FUSE_FINAL=1: += res (fp32 halo), relu, folded 1x1 + sigmoid + normalize -> d_out.
template<int FUSE_FINAL>
__global__ __launch_bounds__(256) void conv3_k(
    const float* __restrict__ in, const unsigned short* __restrict__ wh,
    const unsigned short* __restrict__ wl, const float* __restrict__ bias,
    const float* __restrict__ res, float* __restrict__ out,
    const float* __restrict__ Wf, const float* __restrict__ bff){
  __shared__ __align__(16) char inb[46080];   // 10*18 pix * (64ch hi + 64ch lo) * 2B, swizzled
  __shared__ float facc[8][16][3];
  int tx = blockIdx.x, ty = blockIdx.y, b = blockIdx.z;
  int tid = threadIdx.x;
  int lane = tid & 63, wave = tid >> 6;
  int lo = lane & 15, hi = lane >> 4;
  const int y0 = ty*8, x0 = tx*16;
  const float* ibase = in + (size_t)b*226*226*128;
  if (FUSE_FINAL){
    for (int e = tid; e < 384; e += 256) ((float*)facc)[e] = 0.f;
  }
  f32x4 acc[8][2];
  f32x4 zero = {0.f, 0.f, 0.f, 0.f};
  #pragma unroll
  for (int i = 0; i < 8; ++i){ acc[i][0] = zero; acc[i][1] = zero; }
  int ocb = wave*32;
  for (int ih2 = 0; ih2 < 2; ++ih2){
    __syncthreads();   // previous-iter inb readers done (also orders facc zeroing)
    for (int ch = tid; ch < 1440; ch += 256){
      int pix = ch >> 3, ci = ch & 7;
      int iy = pix/18, ix = pix - iy*18;
      const float* src = ibase + ((size_t)(y0+iy)*226 + (x0+ix))*128 + ih2*64 + ci*8;
      float4 v0 = *(const float4*)(src);
      float4 v1 = *(const float4*)(src + 4);
      float xs[8] = {v0.x, v0.y, v0.z, v0.w, v1.x, v1.y, v1.z, v1.w};
      unsigned short h8[8], l8[8];
      #pragma unroll
      for (int j = 0; j < 8; ++j){
        unsigned short h = f2bf(xs[j]);
        h8[j] = h;
        l8[j] = f2bf(xs[j] - bf2f(h));
      }
      int base = pix*256 + ci*16;
      int swz = (ix & 7) << 4;
      *(bf16x8*)(inb + ((base      ) ^ swz)) = *(bf16x8*)h8;
      *(bf16x8*)(inb + ((base + 128) ^ swz)) = *(bf16x8*)l8;
    }
    __syncthreads();   // staged inb visible
    for (int t = 0; t < 9; ++t){
      int dy = t/3, dx = t - 3*dy;
      for (int pass = 0; pass < 2; ++pass){
        const unsigned short* wsrc = (pass ? wl : wh) + (size_t)(t*2 + ih2)*8192;
        #pragma unroll
        for (int kk = 0; kk < 2; ++kk){
          bf16x8 b0 = *(const bf16x8*)(wsrc + (ocb + lo)*64      + kk*32 + hi*8);
          bf16x8 b1 = *(const bf16x8*)(wsrc + (ocb + 16 + lo)*64 + kk*32 + hi*8);
          int ix = lo + dx;
          int swz = (ix & 7) << 4;
          #pragma unroll
          for (int py = 0; py < 8; ++py){
            int pbase = ((py+dy)*18 + ix)*256;
            bf16x8 ah = *(const bf16x8*)(inb + ((pbase + kk*64 + hi*16) ^ swz));
            acc[py][0] = __builtin_amdgcn_mfma_f32_16x16x32_bf16(ah, b0, acc[py][0], 0, 0, 0);
            acc[py][1] = __builtin_amdgcn_mfma_f32_16x16x32_bf16(ah, b1, acc[py][1], 0, 0, 0);
            if (pass == 0){
              bf16x8 al = *(const bf16x8*)(inb + ((pbase + 128 + kk*64 + hi*16) ^ swz));
              acc[py][0] = __builtin_amdgcn_mfma_f32_16x16x32_bf16(al, b0, acc[py][0], 0, 0, 0);
              acc[py][1] = __builtin_amdgcn_mfma_f32_16x16x32_bf16(al, b1, acc[py][1], 0, 0, 0);
            }
          }
        }
      }
    }
  }
  if (FUSE_FINAL){
    __syncthreads();
    float wf0[2], wf1[2], wf2[2];
    #pragma unroll
    for (int j = 0; j < 2; ++j){
      int oc = ocb + j*16 + lo;
      wf0[j] = Wf[oc]; wf1[j] = Wf[128+oc]; wf2[j] = Wf[256+oc];
    }
    #pragma unroll
    for (int py = 0; py < 8; ++py){
      int gy = ty*8 + py;
      #pragma unroll
      for (int r = 0; r < 4; ++r){
        int px = hi*4 + r;
        int gx = tx*16 + px;
        float p0 = 0.f, p1 = 0.f, p2 = 0.f;
        #pragma unroll
        for (int j = 0; j < 2; ++j){
          int oc = ocb + j*16 + lo;
          float val = acc[py][j][r] + bias[oc]
                    + res[(((size_t)b*226 + gy+1)*226 + (gx+1))*128 + oc];
          val = fmaxf(val, 0.f);
          p0 += val*wf0[j]; p1 += val*wf1[j]; p2 += val*wf2[j];
        }
        #pragma unroll
        for (int s = 1; s < 16; s <<= 1){
          p0 += __shfl_xor(p0, s);
          p1 += __shfl_xor(p1, s);
          p2 += __shfl_xor(p2, s);
        }
        if (lo == 0){
          atomicAdd(&facc[py][px][0], p0);
          atomicAdd(&facc[py][px][1], p1);
          atomicAdd(&facc[py][px][2], p2);
        }
      }
    }
    __syncthreads();
    const float mean3[3] = {0.485f, 0.456f, 0.406f};
    const float istd3[3] = {1.0f/0.229f, 1.0f/0.224f, 1.0f/0.225f};
    for (int e = tid; e < 384; e += 256){
      int py = e / 48;
      int rem = e - py*48;
      int px = rem / 3;
      int ch = rem - px*3;
      float a = facc[py][px][ch] + bff[ch];
      float s = 1.0f/(1.0f + expf(-a));
      out[(((size_t)(b*3 + ch))*224 + (ty*8+py))*224 + (tx*16+px)] = (s - mean3[ch])*istd3[ch];
    }
  } else {
    #pragma unroll
    for (int py = 0; py < 8; ++py){
      int gy = ty*8 + py;
      #pragma unroll
      for (int j = 0; j < 2; ++j){
        int oc = ocb + j*16 + lo;
        float bs = bias[oc];
        #pragma unroll
        for (int r = 0; r < 4; ++r){
          int px = hi*4 + r;
          int gx = tx*16 + px;
          float val = fmaxf(acc[py][j][r] + bs, 0.f);
          out[(((size_t)b*226 + gy+1)*226 + (gx+1))*128 + oc] = val;
        }
      }
    }
  }
}

extern "C" void kernel_launch(void* const* d_in, const int* in_sizes, int n_in,
                              void* d_out, int out_size, void* d_ws, size_t ws_size,
                              hipStream_t stream){
  const float* opc   = (const float*)d_in[0];
  const float* pc    = (const float*)d_in[1];
  const float* Win   = (const float*)d_in[2];
  const float* bin   = (const float*)d_in[3];
  const float* Wg    = (const float*)d_in[4];
  const float* gng   = (const float*)d_in[5];
  const float* gnb   = (const float*)d_in[6];
  const float* Wp    = (const float*)d_in[7];
  const float* bp    = (const float*)d_in[8];
  const float* W1    = (const float*)d_in[9];
  const float* g1    = (const float*)d_in[10];
  const float* b1    = (const float*)d_in[11];
  const float* m1    = (const float*)d_in[12];
  const float* v1    = (const float*)d_in[13];
  const float* W2    = (const float*)d_in[14];
  const float* g2    = (const float*)d_in[15];
  const float* b2    = (const float*)d_in[16];
  const float* m2    = (const float*)d_in[17];
  const float* v2    = (const float*)d_in[18];
  const float* Wimgc = (const float*)d_in[19];
  const float* bimgc = (const float*)d_in[20];
  const float* Wimg  = (const float*)d_in[21];
  const float* bimg  = (const float*)d_in[22];

  char* ws = (char*)d_ws;
  size_t off = 0;
  auto alloc = [&](size_t bytes)->char*{
    char* p = ws + off;
    off += (bytes + 255) & ~(size_t)255;
    return p;
  };
  // total ws usage ~226 MB (round-4 footprint ran OK)
  float* x      = (float*)alloc((size_t)BATCH*NPTS*64*4);
  double* sq    = (double*)alloc((size_t)BATCH*NPTS*8);
  int*   idx    = (int*)  alloc((size_t)BATCH*NPTS*KNN*4);
  float* u      = (float*)alloc((size_t)BATCH*NPTS*128*4);
  float* v      = (float*)alloc((size_t)BATCH*NPTS*128*4);
  float* f      = (float*)alloc((size_t)BATCH*NPTS*128*4);
  float* sums   = (float*)alloc(256);
  double* bnd   = (double*)alloc(256);
  float* bias1  = (float*)alloc(512);
  float* bias2  = (float*)alloc(512);
  float* Wf     = (float*)alloc(2048);
  float* bff    = (float*)alloc(256);
  unsigned short* wh1 = (unsigned short*)alloc((size_t)9*16384*2);
  unsigned short* wl1 = (unsigned short*)alloc((size_t)9*16384*2);
  unsigned short* wh2 = (unsigned short*)alloc((size_t)9*16384*2);
  unsigned short* wl2 = (unsigned short*)alloc((size_t)9*16384*2);
  float* resf = (float*)alloc((size_t)BATCH*226*226*128*4);
  float* h1f  = (float*)alloc((size_t)BATCH*226*226*128*4);
  float* out = (float*)d_out;

  hipMemsetAsync(sums, 0, 256, stream);
  hipMemsetAsync(resf, 0, (size_t)BATCH*226*226*128*4, stream);
  hipMemsetAsync(h1f,  0, (size_t)BATCH*226*226*128*4, stream);

  fold_wpk<<<576, 256, 0, stream>>>(W1, g1, b1, m1, v1, wh1, wl1, bias1);
  fold_wpk<<<576, 256, 0, stream>>>(W2, g2, b2, m2, v2, wh2, wl2, bias2);
  fold_img<<<2, 256, 0, stream>>>(Wimgc, bimgc, Wimg, bimg, Wf, bff);
  prep_x<<<32, 256, 0, stream>>>(opc, Win, bin, x, sq);
  prep_uv<<<4096, 256, 0, stream>>>(x, Wg, u, v);
  knn_k<<<4096, 128, 0, stream>>>(opc, sq, idx);
  stats_k<<<512, 256, 0, stream>>>(u, v, idx, sums);
  fcomp_k<<<512, 256, 0, stream>>>(u, v, idx, sums, gng, gnb, Wp, bp, f);
  bounds_k<<<4, 256, 0, stream>>>(pc, bnd);
  scatter_k<<<2048, 256, 0, stream>>>(pc, bnd, f, resf);
  conv3_k<0><<<dim3(14,28,4), 256, 0, stream>>>(resf, wh1, wl1, bias1, resf, h1f, Wf, bff);
  conv3_k<1><<<dim3(14,28,4), 256, 0, stream>>>(h1f, wh2, wl2, bias2, resf, out, Wf, bff);
}